// Round 9
// baseline (251.111 us; speedup 1.0000x reference)
//
#include <hip/hip_runtime.h>

// SegmentLUT, float-approximation path, 4-deep load pipeline.
//   xf  = med3(rint(x * 1/s), -32768, 32767)
//   idx = #{ j in 0..6 : segment_max[j] < xf }      (searchsorted left)
//   y   = med3(fma(kf[idx], xf, bf[idx]), olo, ohi)
// where kf = alpha * 2^-rs * os, bf = ((beta<<ls)+rbias) * 2^-rs * os.
// Float path deviates from the int reference by <~0.13 abs (measured 0.125)
// vs harness threshold 0.655. Memory floor ~31-35us (65MB fetch + 131MB write).

typedef float f32x4 __attribute__((ext_vector_type(4)));  // clang vector: ok for
                                                          // __builtin_nontemporal_*

__device__ __forceinline__ float seg_one(float x, float inv_s,
                                         float sm0, float sm1, float sm2, float sm3,
                                         float sm4, float sm5, float sm6,
                                         const float2* tab, float olo, float ohi)
{
    float xf = rintf(x * inv_s);                           // v_mul + v_rndne (half-even)
    xf = __builtin_amdgcn_fmed3f(xf, -32768.0f, 32767.0f); // single-inst clamp
    int idx = (sm0 < xf) + (sm1 < xf) + (sm2 < xf) + (sm3 < xf)
            + (sm4 < xf) + (sm5 < xf) + (sm6 < xf);        // idx in [0,7]
    float2 t = tab[idx];                                   // ds_read_b64, conflict-free
    float y = fmaf(t.x, xf, t.y);
    return __builtin_amdgcn_fmed3f(y, olo, ohi);
}

__global__ __launch_bounds__(256) void SegmentLUT_83021717831949_kernel(
    const float* __restrict__ x,
    const float* __restrict__ input_scale,
    const float* __restrict__ out_scale,
    const int*   __restrict__ alpha,
    const int*   __restrict__ beta,
    const int*   __restrict__ lsh,
    const int*   __restrict__ rsh,
    const int*   __restrict__ smax,
    float*       __restrict__ out,
    int n)
{
    __shared__ float2 tab[8];   // {kf, bf} per segment
    float os = out_scale[0];
    if (threadIdx.x < 8) {
        int j  = (int)threadIdx.x;
        int rs = rsh[j];
        int rm1 = rs - 1 > 0 ? rs - 1 : 0;
        int rbias = rs > 0 ? (1 << rm1) : 0;
        int bc = (int)((unsigned)beta[j] << (lsh[j] & 31)) + rbias;  // int32 wrap like ref
        float sc = ldexpf(os, -rs);                                   // os * 2^-rs
        tab[j] = make_float2((float)alpha[j] * sc, (float)bc * sc);
    }
    float inv_s = 1.0f / input_scale[0];   // exact: s is a power of two (2^-13)
    float sm0 = (float)smax[0], sm1 = (float)smax[1], sm2 = (float)smax[2];
    float sm3 = (float)smax[3], sm4 = (float)smax[4], sm5 = (float)smax[5];
    float sm6 = (float)smax[6];
    float olo = -32768.0f * os, ohi = 32767.0f * os;
    __syncthreads();

    int nvec   = n >> 2;
    int stride = (int)(gridDim.x * blockDim.x);
    int tid    = (int)(blockIdx.x * blockDim.x + threadIdx.x);

    const f32x4* __restrict__ xv = (const f32x4*)x;
    f32x4* __restrict__ ov = (f32x4*)out;

#define SEG1(e) seg_one((e), inv_s, sm0, sm1, sm2, sm3, sm4, sm5, sm6, tab, olo, ohi)
#define SEG4(o, v) do { \
        (o).x = SEG1((v).x); (o).y = SEG1((v).y); \
        (o).z = SEG1((v).z); (o).w = SEG1((v).w); } while (0)

    int i = tid;
    // 4-deep batch: 4 independent global_load_dwordx4 in flight per iteration.
    // For this shape (nvec = 8388608, threads = 524288) this runs exactly 4x
    // per thread and the tail loops are empty.
    for (; i + 3 * stride < nvec; i += 4 * stride) {
        f32x4 v0 = xv[i];
        f32x4 v1 = xv[i + stride];
        f32x4 v2 = xv[i + 2 * stride];
        f32x4 v3 = xv[i + 3 * stride];
        f32x4 o0, o1, o2, o3;
        SEG4(o0, v0);
        SEG4(o1, v1);
        SEG4(o2, v2);
        SEG4(o3, v3);
        // Nontemporal: output is never re-read by this kernel; keep it out of
        // L2/L3 so the (restore-resident) input stays cached across replays.
        __builtin_nontemporal_store(o0, &ov[i]);
        __builtin_nontemporal_store(o1, &ov[i + stride]);
        __builtin_nontemporal_store(o2, &ov[i + 2 * stride]);
        __builtin_nontemporal_store(o3, &ov[i + 3 * stride]);
    }
    for (; i < nvec; i += stride) {
        f32x4 v = xv[i];
        f32x4 o;
        SEG4(o, v);
        __builtin_nontemporal_store(o, &ov[i]);
    }
    // Scalar tail for n % 4 != 0 (not hit for this shape).
    for (int k = (nvec << 2) + tid; k < n; k += stride) {
        out[k] = SEG1(x[k]);
    }
#undef SEG4
#undef SEG1
}

extern "C" void kernel_launch(void* const* d_in, const int* in_sizes, int n_in,
                              void* d_out, int out_size, void* d_ws, size_t ws_size,
                              hipStream_t stream) {
    const float* x           = (const float*)d_in[0];
    const float* input_scale = (const float*)d_in[1];
    const float* out_scale   = (const float*)d_in[2];
    const int*   alpha       = (const int*)d_in[3];
    const int*   beta        = (const int*)d_in[4];
    const int*   lsh         = (const int*)d_in[5];
    const int*   rsh         = (const int*)d_in[6];
    const int*   smax        = (const int*)d_in[7];
    float* out = (float*)d_out;

    int n = in_sizes[0];
    int nvec = n >> 2;
    int blocks = (nvec + 255) / 256;
    if (blocks > 2048) blocks = 2048;
    if (blocks < 1) blocks = 1;

    SegmentLUT_83021717831949_kernel<<<blocks, 256, 0, stream>>>(
        x, input_scale, out_scale, alpha, beta, lsh, rsh, smax, out, n);
}

// Round 10
// 228.578 us; speedup vs baseline: 1.0986x; 1.0986x over previous
//
#include <hip/hip_runtime.h>

// SegmentLUT, float path, ONE float4 per thread (no grid-stride loop).
// R9 post-mortem: grid-stride loop serialized on store completion via vmcnt
// issue-order retirement (loads of iter k+1 wait behind stores of iter k).
// One-shot structure removes all intra-thread store->load coupling; BW comes
// from wave turnover like the 6.3-6.7 TB/s copy/fill kernels.
//   xf  = med3(rint(x * 1/s), -32768, 32767)
//   idx = #{ j in 0..6 : segment_max[j] < xf }      (searchsorted left)
//   y   = med3(fma(kf[idx], xf, bf[idx]), olo, ohi)
// kf = alpha * 2^-rs * os, bf = ((beta<<ls)+rbias) * 2^-rs * os.
// absmax vs int reference: 0.125 (threshold 0.655).

typedef float f32x4 __attribute__((ext_vector_type(4)));

__device__ __forceinline__ float seg_one(float x, float inv_s,
                                         float sm0, float sm1, float sm2, float sm3,
                                         float sm4, float sm5, float sm6,
                                         const float2* tab, float olo, float ohi)
{
    float xf = rintf(x * inv_s);                           // v_mul + v_rndne (half-even)
    xf = __builtin_amdgcn_fmed3f(xf, -32768.0f, 32767.0f); // single-inst clamp
    int idx = (sm0 < xf) + (sm1 < xf) + (sm2 < xf) + (sm3 < xf)
            + (sm4 < xf) + (sm5 < xf) + (sm6 < xf);        // idx in [0,7]
    float2 t = tab[idx];                                   // ds_read_b64, conflict-free
    float y = fmaf(t.x, xf, t.y);
    return __builtin_amdgcn_fmed3f(y, olo, ohi);
}

__global__ __launch_bounds__(256) void SegmentLUT_83021717831949_kernel(
    const float* __restrict__ x,
    const float* __restrict__ input_scale,
    const float* __restrict__ out_scale,
    const int*   __restrict__ alpha,
    const int*   __restrict__ beta,
    const int*   __restrict__ lsh,
    const int*   __restrict__ rsh,
    const int*   __restrict__ smax,
    float*       __restrict__ out,
    int n)
{
    int nvec = n >> 2;
    int i = (int)(blockIdx.x * blockDim.x + threadIdx.x);  // vec4 index
    bool valid = i < nvec;

    // Issue the bulk load FIRST so its HBM latency overlaps table setup.
    const f32x4* __restrict__ xv = (const f32x4*)x;
    f32x4 v = {};
    if (valid) v = xv[i];

    __shared__ float2 tab[8];   // {kf, bf} per segment
    float os = out_scale[0];
    if (threadIdx.x < 8) {
        int j  = (int)threadIdx.x;
        int rs = rsh[j];
        int rm1 = rs - 1 > 0 ? rs - 1 : 0;
        int rbias = rs > 0 ? (1 << rm1) : 0;
        int bc = (int)((unsigned)beta[j] << (lsh[j] & 31)) + rbias;  // int32 wrap like ref
        float sc = ldexpf(os, -rs);                                   // os * 2^-rs
        tab[j] = make_float2((float)alpha[j] * sc, (float)bc * sc);
    }
    float inv_s = 1.0f / input_scale[0];   // exact: s is a power of two (2^-13)
    float sm0 = (float)smax[0], sm1 = (float)smax[1], sm2 = (float)smax[2];
    float sm3 = (float)smax[3], sm4 = (float)smax[4], sm5 = (float)smax[5];
    float sm6 = (float)smax[6];
    float olo = -32768.0f * os, ohi = 32767.0f * os;
    __syncthreads();

    if (valid) {
        f32x4 o;
        o.x = seg_one(v.x, inv_s, sm0, sm1, sm2, sm3, sm4, sm5, sm6, tab, olo, ohi);
        o.y = seg_one(v.y, inv_s, sm0, sm1, sm2, sm3, sm4, sm5, sm6, tab, olo, ohi);
        o.z = seg_one(v.z, inv_s, sm0, sm1, sm2, sm3, sm4, sm5, sm6, tab, olo, ohi);
        o.w = seg_one(v.w, inv_s, sm0, sm1, sm2, sm3, sm4, sm5, sm6, tab, olo, ohi);
        ((f32x4*)out)[i] = o;
    }
    // Scalar tail for n % 4 != 0 (empty for this shape: n = 33554432).
    int ntail = n & 3;
    if (ntail && i < ntail) {
        int k = (nvec << 2) + i;
        out[k] = seg_one(x[k], inv_s, sm0, sm1, sm2, sm3, sm4, sm5, sm6, tab, olo, ohi);
    }
}

extern "C" void kernel_launch(void* const* d_in, const int* in_sizes, int n_in,
                              void* d_out, int out_size, void* d_ws, size_t ws_size,
                              hipStream_t stream) {
    const float* x           = (const float*)d_in[0];
    const float* input_scale = (const float*)d_in[1];
    const float* out_scale   = (const float*)d_in[2];
    const int*   alpha       = (const int*)d_in[3];
    const int*   beta        = (const int*)d_in[4];
    const int*   lsh         = (const int*)d_in[5];
    const int*   rsh         = (const int*)d_in[6];
    const int*   smax        = (const int*)d_in[7];
    float* out = (float*)d_out;

    int n = in_sizes[0];
    int nvec = n >> 2;
    int blocks = (nvec + 255) / 256;           // 32768 for this shape: 1 vec4/thread
    if (blocks < 1) blocks = 1;

    SegmentLUT_83021717831949_kernel<<<blocks, 256, 0, stream>>>(
        x, input_scale, out_scale, alpha, beta, lsh, rsh, smax, out, n);
}